// Round 13
// baseline (500.019 us; speedup 1.0000x reference)
//
#include <hip/hip_runtime.h>
#include <hip/hip_fp16.h>
#include <math.h>

#define N_NODES 50000
#define K_NEI   32
#define D_FEAT  128
#define LEAKY   0.01f

#define NPG  3                         // nodes per 32-lane group
#define GPB  8                         // 32-lane groups per 256-thread block
#define NPB  (NPG * GPB)               // 24 nodes per block
#define GRID ((N_NODES + NPB - 1) / NPB)   // 2084 blocks ~ single generation @8/CU

#define CHUNK_SHIFT 12                 // 4096 rows = 1 MB f16 per chunk
#define NCHUNKS     ((N_NODES + (1 << CHUNK_SHIFT) - 1) >> CHUNK_SHIFT)   // 13

// ---------- Phase 1: g = feat.a_nei, h = feat.a_ref, fh = f16(feat) ----------
__global__ __launch_bounds__(256) void precompute_kernel(
    const float* __restrict__ feat,
    const float* __restrict__ att,
    unsigned short* __restrict__ fh,
    float* __restrict__ g,
    float* __restrict__ h)
{
    const int lane = threadIdx.x & 31;
    const int row  = blockIdx.x * 8 + (threadIdx.x >> 5);
    if (row >= N_NODES) return;

    const float4 a_ref = *(const float4*)&att[4 * lane];
    const float4 a_nei = *(const float4*)&att[D_FEAT + 4 * lane];
    const float4 f     = *(const float4*)&feat[(size_t)row * D_FEAT + 4 * lane];

    float sr = f.x * a_ref.x + f.y * a_ref.y + f.z * a_ref.z + f.w * a_ref.w;
    float sn = f.x * a_nei.x + f.y * a_nei.y + f.z * a_nei.z + f.w * a_nei.w;
    #pragma unroll
    for (int off = 16; off >= 1; off >>= 1) {
        sr += __shfl_xor(sr, off, 32);
        sn += __shfl_xor(sn, off, 32);
    }
    if (lane == 0) { h[row] = sr; g[row] = sn; }

    const __half2 p0 = __floats2half2_rn(f.x, f.y);
    const __half2 p1 = __floats2half2_rn(f.z, f.w);
    uint2 st;
    st.x = *(const unsigned*)&p0;
    st.y = *(const unsigned*)&p1;
    *(uint2*)&fh[(size_t)row * D_FEAT + 4 * lane] = st;
}

// o.xyzw += wgt * f16x4(v)   (v_fma_mix_f32)
__device__ __forceinline__ void acc4(float4& o, float wgt, uint2 v) {
    const __half2 h0 = *(const __half2*)&v.x;
    const __half2 h1 = *(const __half2*)&v.y;
    o.x += wgt * __half2float(h0.x);
    o.y += wgt * __half2float(h0.y);
    o.z += wgt * __half2float(h1.x);
    o.w += wgt * __half2float(h1.y);
}

// ---------- Phase 2: LDS rank-sorted pairs, SW-pipelined f16 gather ----------
__global__ __launch_bounds__(256, 8) void gather_lds(
    const unsigned short* __restrict__ fh,
    const int*   __restrict__ nei,
    const float* __restrict__ g,
    const float* __restrict__ h,
    float*       __restrict__ out)
{
    // 32 B per rank: [0]={i0,w0,i1,w1}  [1]={i2,w2,-,-}  -> b128 + b64 reads
    __shared__ uint4 prs[GPB][K_NEI][2];   // 8 KB

    const int lane       = threadIdx.x & 31;
    const int grp        = threadIdx.x >> 5;       // 0..7
    const int group      = blockIdx.x * GPB + grp;
    const int half_shift = threadIdx.x & 32;       // 0 lower half, 32 upper half
    const int node0      = group * NPG;
    const unsigned lt    = (1u << lane) - 1u;

    // ---- setup: weights + chunk-sort rank, scatter (idx,w) into LDS ----
    #pragma unroll
    for (int j = 0; j < NPG; ++j) {
        const int  node  = node0 + j;
        const bool valid = (node < N_NODES);

        const int idx = valid ? nei[node * K_NEI + lane] : 0;
        float sc = valid ? (h[node] + g[idx]) : 0.f;
        sc = (sc >= 0.f) ? sc : LEAKY * sc;
        const float p = __expf(sc);          // no-max softmax: |score| small, f32-safe
        float denom = p;
        #pragma unroll
        for (int off = 16; off >= 1; off >>= 1)
            denom += __shfl_xor(denom, off, 32);
        const float w = valid ? (p / denom) : 0.f;   // phantom node: weight 0

        const int cid = idx >> CHUNK_SHIFT;
        int rank = 0;
        #pragma unroll
        for (int c = 0; c < NCHUNKS; ++c) {
            const unsigned long long b = __ballot(cid == c);
            const unsigned bh = (unsigned)(b >> half_shift);
            rank += (c < cid)  ? __popc(bh)      : 0;
            rank += (c == cid) ? __popc(bh & lt) : 0;
        }
        ((uint2*)&prs[grp][rank][0])[j] = make_uint2((unsigned)idx, __float_as_uint(w));
    }
    __syncthreads();

    // ---- distance-2 software-pipelined gather in (approx) chunk order ----
    float4 o0 = make_float4(0.f, 0.f, 0.f, 0.f);
    float4 o1 = make_float4(0.f, 0.f, 0.f, 0.f);
    float4 o2 = make_float4(0.f, 0.f, 0.f, 0.f);

    const char* fbase = (const char*)fh;
    const unsigned lbyte = (unsigned)(lane << 3);  // byte offset of this lane's 8 B

    uint4 PA = prs[grp][0][0];
    uint2 QA = *(const uint2*)&prs[grp][0][1];
    uint2 a0 = *(const uint2*)(fbase + ((PA.x << 8) + lbyte));
    uint2 a1 = *(const uint2*)(fbase + ((PA.z << 8) + lbyte));
    uint2 a2 = *(const uint2*)(fbase + ((QA.x << 8) + lbyte));

    uint4 PB = prs[grp][1][0];
    uint2 QB = *(const uint2*)&prs[grp][1][1];
    uint2 b0 = *(const uint2*)(fbase + ((PB.x << 8) + lbyte));
    uint2 b1 = *(const uint2*)(fbase + ((PB.z << 8) + lbyte));
    uint2 b2 = *(const uint2*)(fbase + ((QB.x << 8) + lbyte));

    #pragma unroll
    for (int i = 0; i < K_NEI; i += 2) {
        const float wA0 = __uint_as_float(PA.y);
        const float wA1 = __uint_as_float(PA.w);
        const float wA2 = __uint_as_float(QA.y);
        const uint2 uA0 = a0, uA1 = a1, uA2 = a2;
        if (i + 2 < K_NEI) {                      // reload A-slot (rank i+2)
            PA = prs[grp][i + 2][0];
            QA = *(const uint2*)&prs[grp][i + 2][1];
            a0 = *(const uint2*)(fbase + ((PA.x << 8) + lbyte));
            a1 = *(const uint2*)(fbase + ((PA.z << 8) + lbyte));
            a2 = *(const uint2*)(fbase + ((QA.x << 8) + lbyte));
        }
        acc4(o0, wA0, uA0); acc4(o1, wA1, uA1); acc4(o2, wA2, uA2);

        const float wB0 = __uint_as_float(PB.y);
        const float wB1 = __uint_as_float(PB.w);
        const float wB2 = __uint_as_float(QB.y);
        const uint2 uB0 = b0, uB1 = b1, uB2 = b2;
        if (i + 3 < K_NEI) {                      // reload B-slot (rank i+3)
            PB = prs[grp][i + 3][0];
            QB = *(const uint2*)&prs[grp][i + 3][1];
            b0 = *(const uint2*)(fbase + ((PB.x << 8) + lbyte));
            b1 = *(const uint2*)(fbase + ((PB.z << 8) + lbyte));
            b2 = *(const uint2*)(fbase + ((QB.x << 8) + lbyte));
        }
        acc4(o0, wB0, uB0); acc4(o1, wB1, uB1); acc4(o2, wB2, uB2);
    }

    // ---- ELU + guarded store ----
    {
        float4 r;
        r.x = (o0.x > 0.f) ? o0.x : (__expf(o0.x) - 1.f);
        r.y = (o0.y > 0.f) ? o0.y : (__expf(o0.y) - 1.f);
        r.z = (o0.z > 0.f) ? o0.z : (__expf(o0.z) - 1.f);
        r.w = (o0.w > 0.f) ? o0.w : (__expf(o0.w) - 1.f);
        if (node0 + 0 < N_NODES)
            *(float4*)&out[(size_t)(node0 + 0) * D_FEAT + 4 * lane] = r;
        r.x = (o1.x > 0.f) ? o1.x : (__expf(o1.x) - 1.f);
        r.y = (o1.y > 0.f) ? o1.y : (__expf(o1.y) - 1.f);
        r.z = (o1.z > 0.f) ? o1.z : (__expf(o1.z) - 1.f);
        r.w = (o1.w > 0.f) ? o1.w : (__expf(o1.w) - 1.f);
        if (node0 + 1 < N_NODES)
            *(float4*)&out[(size_t)(node0 + 1) * D_FEAT + 4 * lane] = r;
        r.x = (o2.x > 0.f) ? o2.x : (__expf(o2.x) - 1.f);
        r.y = (o2.y > 0.f) ? o2.y : (__expf(o2.y) - 1.f);
        r.z = (o2.z > 0.f) ? o2.z : (__expf(o2.z) - 1.f);
        r.w = (o2.w > 0.f) ? o2.w : (__expf(o2.w) - 1.f);
        if (node0 + 2 < N_NODES)
            *(float4*)&out[(size_t)(node0 + 2) * D_FEAT + 4 * lane] = r;
    }
}

// ---------- Fallback (round-1 kernel) if workspace too small ----------
__global__ __launch_bounds__(256, 4) void feat_encoder_fallback(
    const float* __restrict__ feat,
    const int*   __restrict__ nei,
    const float* __restrict__ att,
    float*       __restrict__ out)
{
    const int lane = threadIdx.x & 31;
    const int node = blockIdx.x * 8 + (threadIdx.x >> 5);
    if (node >= N_NODES) return;

    const float4 a_ref = *(const float4*)&att[4 * lane];
    const float4 a_nei = *(const float4*)&att[D_FEAT + 4 * lane];

    const float4 f = *(const float4*)&feat[(size_t)node * D_FEAT + 4 * lane];
    float sref = f.x * a_ref.x + f.y * a_ref.y + f.z * a_ref.z + f.w * a_ref.w;
    #pragma unroll
    for (int off = 16; off >= 1; off >>= 1)
        sref += __shfl_xor(sref, off, 32);

    const int idx = nei[node * K_NEI + lane];
    float  s = 0.f;
    float4 o = {0.f, 0.f, 0.f, 0.f};
    #pragma unroll
    for (int k = 0; k < K_NEI; ++k) {
        const int nk = __shfl(idx, k, 32);
        const float4 v = *(const float4*)&feat[(size_t)nk * D_FEAT + 4 * lane];
        float partial = v.x * a_nei.x + v.y * a_nei.y + v.z * a_nei.z + v.w * a_nei.w;
        #pragma unroll
        for (int off = 16; off >= 1; off >>= 1)
            partial += __shfl_xor(partial, off, 32);
        float score = partial + sref;
        score = (score >= 0.f) ? score : LEAKY * score;
        const float p = __expf(score);
        s += p;
        o.x += p * v.x; o.y += p * v.y; o.z += p * v.z; o.w += p * v.w;
    }
    const float inv = 1.0f / s;
    float4 r;
    r.x = o.x * inv; r.y = o.y * inv; r.z = o.z * inv; r.w = o.w * inv;
    r.x = (r.x > 0.f) ? r.x : expm1f(r.x);
    r.y = (r.y > 0.f) ? r.y : expm1f(r.y);
    r.z = (r.z > 0.f) ? r.z : expm1f(r.z);
    r.w = (r.w > 0.f) ? r.w : expm1f(r.w);
    *(float4*)&out[(size_t)node * D_FEAT + 4 * lane] = r;
}

extern "C" void kernel_launch(void* const* d_in, const int* in_sizes, int n_in,
                              void* d_out, int out_size, void* d_ws, size_t ws_size,
                              hipStream_t stream) {
    const float* feat = (const float*)d_in[0];
    const int*   nei  = (const int*)d_in[1];
    const float* att  = (const float*)d_in[2];
    float*       out  = (float*)d_out;

    const size_t fh_bytes = (size_t)N_NODES * D_FEAT * sizeof(unsigned short); // 12.8 MB
    const size_t g_bytes  = (size_t)N_NODES * sizeof(float);                   // 200 KB
    const size_t need     = fh_bytes + 2 * g_bytes;

    if (ws_size >= need) {
        unsigned short* fh = (unsigned short*)d_ws;
        float* g = (float*)((char*)d_ws + fh_bytes);
        float* h = (float*)((char*)d_ws + fh_bytes + g_bytes);
        precompute_kernel<<<dim3((N_NODES + 7) / 8), 256, 0, stream>>>(feat, att, fh, g, h);
        gather_lds<<<dim3(GRID), 256, 0, stream>>>(fh, nei, g, h, out);
    } else {
        feat_encoder_fallback<<<dim3((N_NODES + 7) / 8), 256, 0, stream>>>(feat, nei, att, out);
    }
}

// Round 14
// 54.293 us; speedup vs baseline: 9.2096x; 9.2096x over previous
//
#include <hip/hip_runtime.h>
#include <hip/hip_fp16.h>
#include <math.h>

#define N_NODES 50000
#define K_NEI   32
#define D_FEAT  128
#define LEAKY   0.01f

#define NPG  2                         // nodes per 32-lane group
#define GPB  8                         // 32-lane groups per 256-thread block
#define NPB  (NPG * GPB)               // 16 nodes per block
#define GRID (N_NODES / NPB)           // 3125 blocks exactly (50000 = 3125*16)

#define CHUNK_SHIFT 12                 // 4096 rows = 1 MB f16 per chunk
#define NCHUNKS     ((N_NODES + (1 << CHUNK_SHIFT) - 1) >> CHUNK_SHIFT)   // 13

// ---------- Phase 1: g = feat.a_nei, h = feat.a_ref, fh = f16(feat) ----------
__global__ __launch_bounds__(256) void precompute_kernel(
    const float* __restrict__ feat,
    const float* __restrict__ att,
    unsigned short* __restrict__ fh,
    float* __restrict__ g,
    float* __restrict__ h)
{
    const int lane = threadIdx.x & 31;
    const int row  = blockIdx.x * 8 + (threadIdx.x >> 5);
    if (row >= N_NODES) return;

    const float4 a_ref = *(const float4*)&att[4 * lane];
    const float4 a_nei = *(const float4*)&att[D_FEAT + 4 * lane];
    const float4 f     = *(const float4*)&feat[(size_t)row * D_FEAT + 4 * lane];

    float sr = f.x * a_ref.x + f.y * a_ref.y + f.z * a_ref.z + f.w * a_ref.w;
    float sn = f.x * a_nei.x + f.y * a_nei.y + f.z * a_nei.z + f.w * a_nei.w;
    #pragma unroll
    for (int off = 16; off >= 1; off >>= 1) {
        sr += __shfl_xor(sr, off, 32);
        sn += __shfl_xor(sn, off, 32);
    }
    if (lane == 0) { h[row] = sr; g[row] = sn; }

    const __half2 p0 = __floats2half2_rn(f.x, f.y);
    const __half2 p1 = __floats2half2_rn(f.z, f.w);
    uint2 st;
    st.x = *(const unsigned*)&p0;
    st.y = *(const unsigned*)&p1;
    *(uint2*)&fh[(size_t)row * D_FEAT + 4 * lane] = st;
}

// ---------- Phase 2: half-wave 16B gather, LDS rank-sorted pairs -------------
__global__ __launch_bounds__(256, 8) void gather_lds(
    const unsigned short* __restrict__ fh,
    const int*   __restrict__ nei,
    const float* __restrict__ g,
    const float* __restrict__ h,
    float*       __restrict__ out)
{
    // pairs4[grp][rank] = {idx0, w0, idx1, w1}
    __shared__ uint4 pairs4[GPB][K_NEI];   // 4 KB

    const int lane       = threadIdx.x & 31;
    const int grp        = threadIdx.x >> 5;       // 0..7
    const int group      = blockIdx.x * GPB + grp;
    const int half_shift = threadIdx.x & 32;       // 0 lower half-wave, 32 upper
    const int node0      = group * NPG;
    const unsigned lt    = (1u << lane) - 1u;

    // ---- setup: weights + chunk-sort rank, scatter (idx,w) into LDS ----
    #pragma unroll
    for (int j = 0; j < NPG; ++j) {
        const int node = node0 + j;                // grid covers N exactly

        const int idx = nei[node * K_NEI + lane];
        float sc = h[node] + g[idx];
        sc = (sc >= 0.f) ? sc : LEAKY * sc;
        const float p = __expf(sc);          // no-max softmax: |score| small, f32-safe
        float denom = p;
        #pragma unroll
        for (int off = 16; off >= 1; off >>= 1)
            denom += __shfl_xor(denom, off, 32);
        const float w = p / denom;

        const int cid = idx >> CHUNK_SHIFT;
        int rank = 0;
        #pragma unroll
        for (int c = 0; c < NCHUNKS; ++c) {
            const unsigned long long b = __ballot(cid == c);
            const unsigned bh = (unsigned)(b >> half_shift);
            rank += (c < cid)  ? __popc(bh)      : 0;
            rank += (c == cid) ? __popc(bh & lt) : 0;
        }
        ((uint2*)&pairs4[grp][rank])[j] = make_uint2((unsigned)idx, __float_as_uint(w));
    }
    __syncthreads();

    // ---- half-wave gather: lanes 0-15 -> node0, lanes 16-31 -> node1 ----
    // each lane loads 16 B (8 halves) of its node's row per rank: one VMEM
    // instruction serves both nodes.
    const int hl  = lane & 15;                 // lane within half-group
    const int sel = (lane >> 4) & 1;           // 0: node0, 1: node1

    float4 olo = make_float4(0.f, 0.f, 0.f, 0.f);
    float4 ohi = make_float4(0.f, 0.f, 0.f, 0.f);

    const char* fbase = (const char*)fh;
    const unsigned lbyte = (unsigned)(hl << 4);   // 16 B per half-lane

    #pragma unroll 8
    for (int i = 0; i < K_NEI; ++i) {
        const uint4 t = pairs4[grp][i];           // uniform ds_read_b128
        const unsigned ridx = sel ? t.z : t.x;
        const float    wk   = __uint_as_float(sel ? t.w : t.y);
        const uint4 v = *(const uint4*)(fbase + ((ridx << 8) + lbyte));

        const __half2 h0 = *(const __half2*)&v.x;
        const __half2 h1 = *(const __half2*)&v.y;
        const __half2 h2 = *(const __half2*)&v.z;
        const __half2 h3 = *(const __half2*)&v.w;
        olo.x += wk * __half2float(h0.x);         // v_fma_mix_f32
        olo.y += wk * __half2float(h0.y);
        olo.z += wk * __half2float(h1.x);
        olo.w += wk * __half2float(h1.y);
        ohi.x += wk * __half2float(h2.x);
        ohi.y += wk * __half2float(h2.y);
        ohi.z += wk * __half2float(h3.x);
        ohi.w += wk * __half2float(h3.y);
    }

    // ---- ELU + store: lane owns 8 consecutive d of its node ----
    const int node = node0 + sel;
    float4 r0, r1;
    r0.x = (olo.x > 0.f) ? olo.x : (__expf(olo.x) - 1.f);
    r0.y = (olo.y > 0.f) ? olo.y : (__expf(olo.y) - 1.f);
    r0.z = (olo.z > 0.f) ? olo.z : (__expf(olo.z) - 1.f);
    r0.w = (olo.w > 0.f) ? olo.w : (__expf(olo.w) - 1.f);
    r1.x = (ohi.x > 0.f) ? ohi.x : (__expf(ohi.x) - 1.f);
    r1.y = (ohi.y > 0.f) ? ohi.y : (__expf(ohi.y) - 1.f);
    r1.z = (ohi.z > 0.f) ? ohi.z : (__expf(ohi.z) - 1.f);
    r1.w = (ohi.w > 0.f) ? ohi.w : (__expf(ohi.w) - 1.f);

    float* op = &out[(size_t)node * D_FEAT + hl * 8];
    *(float4*)op       = r0;
    *(float4*)(op + 4) = r1;
}

// ---------- Fallback (round-1 kernel) if workspace too small ----------
__global__ __launch_bounds__(256, 4) void feat_encoder_fallback(
    const float* __restrict__ feat,
    const int*   __restrict__ nei,
    const float* __restrict__ att,
    float*       __restrict__ out)
{
    const int lane = threadIdx.x & 31;
    const int node = blockIdx.x * 8 + (threadIdx.x >> 5);
    if (node >= N_NODES) return;

    const float4 a_ref = *(const float4*)&att[4 * lane];
    const float4 a_nei = *(const float4*)&att[D_FEAT + 4 * lane];

    const float4 f = *(const float4*)&feat[(size_t)node * D_FEAT + 4 * lane];
    float sref = f.x * a_ref.x + f.y * a_ref.y + f.z * a_ref.z + f.w * a_ref.w;
    #pragma unroll
    for (int off = 16; off >= 1; off >>= 1)
        sref += __shfl_xor(sref, off, 32);

    const int idx = nei[node * K_NEI + lane];
    float  s = 0.f;
    float4 o = {0.f, 0.f, 0.f, 0.f};
    #pragma unroll
    for (int k = 0; k < K_NEI; ++k) {
        const int nk = __shfl(idx, k, 32);
        const float4 v = *(const float4*)&feat[(size_t)nk * D_FEAT + 4 * lane];
        float partial = v.x * a_nei.x + v.y * a_nei.y + v.z * a_nei.z + v.w * a_nei.w;
        #pragma unroll
        for (int off = 16; off >= 1; off >>= 1)
            partial += __shfl_xor(partial, off, 32);
        float score = partial + sref;
        score = (score >= 0.f) ? score : LEAKY * score;
        const float p = __expf(score);
        s += p;
        o.x += p * v.x; o.y += p * v.y; o.z += p * v.z; o.w += p * v.w;
    }
    const float inv = 1.0f / s;
    float4 r;
    r.x = o.x * inv; r.y = o.y * inv; r.z = o.z * inv; r.w = o.w * inv;
    r.x = (r.x > 0.f) ? r.x : expm1f(r.x);
    r.y = (r.y > 0.f) ? r.y : expm1f(r.y);
    r.z = (r.z > 0.f) ? r.z : expm1f(r.z);
    r.w = (r.w > 0.f) ? r.w : expm1f(r.w);
    *(float4*)&out[(size_t)node * D_FEAT + 4 * lane] = r;
}

extern "C" void kernel_launch(void* const* d_in, const int* in_sizes, int n_in,
                              void* d_out, int out_size, void* d_ws, size_t ws_size,
                              hipStream_t stream) {
    const float* feat = (const float*)d_in[0];
    const int*   nei  = (const int*)d_in[1];
    const float* att  = (const float*)d_in[2];
    float*       out  = (float*)d_out;

    const size_t fh_bytes = (size_t)N_NODES * D_FEAT * sizeof(unsigned short); // 12.8 MB
    const size_t g_bytes  = (size_t)N_NODES * sizeof(float);                   // 200 KB
    const size_t need     = fh_bytes + 2 * g_bytes;

    if (ws_size >= need) {
        unsigned short* fh = (unsigned short*)d_ws;
        float* g = (float*)((char*)d_ws + fh_bytes);
        float* h = (float*)((char*)d_ws + fh_bytes + g_bytes);
        precompute_kernel<<<dim3((N_NODES + 7) / 8), 256, 0, stream>>>(feat, att, fh, g, h);
        gather_lds<<<dim3(GRID), 256, 0, stream>>>(fh, nei, g, h, out);
    } else {
        feat_encoder_fallback<<<dim3((N_NODES + 7) / 8), 256, 0, stream>>>(feat, nei, att, out);
    }
}